// Round 1
// baseline (249.622 us; speedup 1.0000x reference)
//
#include <hip/hip_runtime.h>
#include <stdint.h>

#define NROWS 8192
#define DIM   2048
#define MARGIN 2.0f
#define BT 128
#define BK 64
#define NT (NROWS / BT)              // 64 tiles per dim
#define NTILES (NT * (NT + 1) / 2)   // 2080 upper-tri tiles

typedef __attribute__((ext_vector_type(8))) short short8;   // 8 bf16 (A/B frag)
typedef __attribute__((ext_vector_type(4))) float floatx4;  // C/D frag

__device__ __forceinline__ ushort f2bf(float x) {
    uint32_t u = __float_as_uint(x);
    uint32_t r = u + 0x7fffu + ((u >> 16) & 1u);   // RNE
    return (ushort)(r >> 16);
}
__device__ __forceinline__ float bf2f(ushort b) {
    return __uint_as_float(((uint32_t)b) << 16);
}

// ---------------- kernel 1: fp32 -> bf16 cast + row sum of squares ----------
__global__ __launch_bounds__(256) void prep_kernel(const float* __restrict__ p,
                                                   ushort* __restrict__ pb,
                                                   float* __restrict__ sq) {
    int row = blockIdx.x;
    int t = threadIdx.x;
    const float4* prow = (const float4*)(p + (size_t)row * DIM);
    ushort* brow = pb + (size_t)row * DIM;
    float s = 0.f;
#pragma unroll
    for (int h = 0; h < 2; ++h) {
        int idx = h * 256 + t;               // float4 index within row
        float4 v = prow[idx];
        ushort4 o;
        o.x = f2bf(v.x); o.y = f2bf(v.y); o.z = f2bf(v.z); o.w = f2bf(v.w);
        float a = bf2f(o.x), b = bf2f(o.y), c = bf2f(o.z), d = bf2f(o.w);
        s += a * a + b * b + c * c + d * d;  // sumsq of the ROUNDED values
        *(ushort4*)(brow + idx * 4) = o;
    }
#pragma unroll
    for (int o = 32; o > 0; o >>= 1) s += __shfl_down(s, o, 64);
    __shared__ float wsums[4];
    int lane = t & 63, wv = t >> 6;
    if (lane == 0) wsums[wv] = s;
    __syncthreads();
    if (t == 0) sq[row] = wsums[0] + wsums[1] + wsums[2] + wsums[3];
}

// ---------------- kernel 2: triangular tiled Gram + fused loss --------------
__device__ __forceinline__ void stage_tile(const ushort* __restrict__ src,
                                           ushort* lds, int wv, int lane) {
    // 16 KB tile = 16 chunks of 1KB; 4 waves x 4 issues; lane l -> LDS base + l*16B
#pragma unroll
    for (int i = 0; i < 4; ++i) {
        int cc = i * 4 + wv;
        const ushort* g = src + (size_t)(cc * 8 + (lane >> 3)) * DIM + (lane & 7) * 8;
        ushort* l = lds + cc * 512;          // wave-uniform base
        __builtin_amdgcn_global_load_lds(
            (const __attribute__((address_space(1))) uint32_t*)g,
            (__attribute__((address_space(3))) uint32_t*)l, 16, 0, 0);
    }
}

__global__ __launch_bounds__(256) void tile_kernel(
    const ushort* __restrict__ pb, const float* __restrict__ sq,
    const int* __restrict__ gt, double* __restrict__ accum) {

    __shared__ ushort lA[BT * BK];
    __shared__ ushort lB[BT * BK];
    __shared__ float wsum[4];

    int bid = (int)blockIdx.x;
    // bijective XCD swizzle (NTILES % 8 == 0)
    bid = (bid & 7) * (NTILES / 8) + (bid >> 3);

    // decode triangular (ti <= tj): off(r) = r*NT - r(r-1)/2
    float fn = (float)NT + 0.5f;
    int r = (int)(fn - sqrtf(fn * fn - 2.0f * (float)bid));
    if (r < 0) r = 0;
    if (r >= NT) r = NT - 1;
    while ((r + 1) * NT - ((r + 1) * r) / 2 <= bid) ++r;
    while (r * NT - (r * (r - 1)) / 2 > bid) --r;
    int ti = r;
    int tj = r + (bid - (r * NT - (r * (r - 1)) / 2));

    int t = threadIdx.x;
    int lane = t & 63;
    int wv = t >> 6;
    int wrow = (wv >> 1) * 64;   // wave's 64x64 sub-tile
    int wcol = (wv & 1) * 64;

    const ushort* Abase = pb + (size_t)ti * BT * DIM;
    const ushort* Bbase = pb + (size_t)tj * BT * DIM;

    floatx4 acc[4][4] = {};

    for (int k0 = 0; k0 < DIM; k0 += BK) {
        stage_tile(Abase + k0, lA, wv, lane);
        stage_tile(Bbase + k0, lB, wv, lane);
        __syncthreads();
#pragma unroll
        for (int ks = 0; ks < 2; ++ks) {
            int kof = ks * 32 + (lane >> 4) * 8;
            short8 af[4], bfr[4];
#pragma unroll
            for (int m = 0; m < 4; ++m)
                af[m] = *(const short8*)&lA[(wrow + m * 16 + (lane & 15)) * BK + kof];
#pragma unroll
            for (int n = 0; n < 4; ++n)
                bfr[n] = *(const short8*)&lB[(wcol + n * 16 + (lane & 15)) * BK + kof];
#pragma unroll
            for (int m = 0; m < 4; ++m)
#pragma unroll
                for (int n = 0; n < 4; ++n)
                    acc[m][n] = __builtin_amdgcn_mfma_f32_16x16x32_bf16(
                        af[m], bfr[n], acc[m][n], 0, 0, 0);
        }
        __syncthreads();
    }

    // fused epilogue: d2 -> contrastive term -> weighted partial sum
    const float invd = 1.0f / (float)DIM;
    int ibase = ti * BT + wrow + (lane >> 4) * 4;   // C row = (lane>>4)*4 + reg
    int jbase = tj * BT + wcol + (lane & 15);       // C col = lane&15
    float sqj[4]; int gj[4];
#pragma unroll
    for (int n = 0; n < 4; ++n) {
        int j = jbase + n * 16;
        sqj[n] = sq[j]; gj[n] = gt[j];
    }

    float lsum = 0.f;
#pragma unroll
    for (int m = 0; m < 4; ++m) {
#pragma unroll
        for (int rr = 0; rr < 4; ++rr) {
            int i = ibase + m * 16 + rr;
            float sqi = sq[i];
            int gi = gt[i];
#pragma unroll
            for (int n = 0; n < 4; ++n) {
                int j = jbase + n * 16;
                float d2 = fmaxf(sqi + sqj[n] - 2.0f * acc[m][n][rr], 0.0f) * invd;
                float term = (gi == gj[n]) ? d2 : fmaxf(MARGIN - d2, 0.0f);
                // off-diag tile counted twice (mirror); diagonal elements twice
                // (reference includes diagonal in triu; loss = S/(B*(B-1)))
                float wgt = (ti != tj) ? 2.0f : ((i == j) ? 2.0f : 1.0f);
                lsum += wgt * term;
            }
        }
    }
#pragma unroll
    for (int o = 32; o > 0; o >>= 1) lsum += __shfl_down(lsum, o, 64);
    if (lane == 0) wsum[wv] = lsum;
    __syncthreads();
    if (t == 0) atomicAdd(accum, (double)(wsum[0] + wsum[1] + wsum[2] + wsum[3]));
}

// ---------------- kernel 3: finalize ----------------------------------------
__global__ void finalize_kernel(const double* __restrict__ accum,
                                float* __restrict__ out) {
    if (threadIdx.x == 0)
        out[0] = (float)(accum[0] * (1.0 / ((double)NROWS * (double)(NROWS - 1))));
}

extern "C" void kernel_launch(void* const* d_in, const int* in_sizes, int n_in,
                              void* d_out, int out_size, void* d_ws, size_t ws_size,
                              hipStream_t stream) {
    (void)in_sizes; (void)n_in; (void)out_size; (void)ws_size;
    const float* p = (const float*)d_in[0];
    const int* gt = (const int*)d_in[1];
    float* out = (float*)d_out;

    ushort* pb = (ushort*)d_ws;                                   // 32 MB bf16
    float* sq = (float*)((char*)d_ws + (size_t)NROWS * DIM * 2);  // 32 KB
    double* accum = (double*)((char*)d_ws + (size_t)NROWS * DIM * 2
                              + (size_t)NROWS * sizeof(float));   // 8 B

    hipMemsetAsync(accum, 0, sizeof(double), stream);
    prep_kernel<<<NROWS, 256, 0, stream>>>(p, pb, sq);
    tile_kernel<<<NTILES, 256, 0, stream>>>(pb, sq, gt, accum);
    finalize_kernel<<<1, 64, 0, stream>>>(accum, out);
}

// Round 3
// 199.263 us; speedup vs baseline: 1.2527x; 1.2527x over previous
//
#include <hip/hip_runtime.h>
#include <stdint.h>

#define NROWS 8192
#define DIM   2048
#define MARGIN 2.0f

// ---- 256x256 8-phase tile kernel geometry ----
#define BT2     256
#define BK2     64
#define NKT     (DIM / BK2)              // 32 K-tiles
#define NT2     (NROWS / BT2)            // 32 tile-rows
#define NTILES2 (NT2 * (NT2 + 1) / 2)    // 528 upper-tri tiles
#define ABUF_EL 16384                    // 256*64 elements (A region per buffer)
#define BUF_EL  32768                    // A + B regions per buffer
#define HALF_EL 8192                     // 128*64 elements per half-tile

typedef __attribute__((ext_vector_type(8))) short short8;   // 8 bf16
typedef __attribute__((ext_vector_type(4))) float floatx4;  // C/D frag

__device__ __forceinline__ ushort f2bf(float x) {
    uint32_t u = __float_as_uint(x);
    uint32_t r = u + 0x7fffu + ((u >> 16) & 1u);   // RNE
    return (ushort)(r >> 16);
}
__device__ __forceinline__ float bf2f(ushort b) {
    return __uint_as_float(((uint32_t)b) << 16);
}

// ---------------- kernel 1: fp32 -> bf16 cast + row sum of squares ----------
__global__ __launch_bounds__(256) void prep_kernel(const float* __restrict__ p,
                                                   ushort* __restrict__ pb,
                                                   float* __restrict__ sq) {
    int row = blockIdx.x;
    int t = threadIdx.x;
    const float4* prow = (const float4*)(p + (size_t)row * DIM);
    ushort* brow = pb + (size_t)row * DIM;
    float s = 0.f;
#pragma unroll
    for (int h = 0; h < 2; ++h) {
        int idx = h * 256 + t;
        float4 v = prow[idx];
        ushort4 o;
        o.x = f2bf(v.x); o.y = f2bf(v.y); o.z = f2bf(v.z); o.w = f2bf(v.w);
        float a = bf2f(o.x), b = bf2f(o.y), c = bf2f(o.z), d = bf2f(o.w);
        s += a * a + b * b + c * c + d * d;   // sumsq of ROUNDED values
        *(ushort4*)(brow + idx * 4) = o;
    }
#pragma unroll
    for (int o = 32; o > 0; o >>= 1) s += __shfl_down(s, o, 64);
    __shared__ float wsums[4];
    int lane = t & 63, wvv = t >> 6;
    if (lane == 0) wsums[wvv] = s;
    __syncthreads();
    if (t == 0) sq[row] = wsums[0] + wsums[1] + wsums[2] + wsums[3];
}

// ---------------- half-tile stage: global -> LDS (linear dest, pre-swizzled src)
// which: 0 = A half0, 1 = A half1, 2 = B half0, 3 = B half1, for K-tile t.
// t >= NKT clamps to t-2: same buffer/region (t parity preserved), data dead.
__device__ __forceinline__ void stage_ht(const ushort* __restrict__ pb,
                                         ushort* lds, int t, int which,
                                         int ibase, int jbase, int tid) {
    if (t >= NKT) t -= 2;
    const int h = which & 1;
    const int row0 = ((which >= 2) ? jbase : ibase) + h * 128;
    const ushort* g0 = pb + (size_t)row0 * DIM + t * BK2;
    ushort* l0 = lds + (t & 1) * BUF_EL + ((which >= 2) ? ABUF_EL : 0) + h * HALF_EL;
#pragma unroll
    for (int r = 0; r < 2; ++r) {
        int row = r * 64 + (tid >> 3);                 // row within half-tile
        int c8 = (tid & 7) ^ ((tid >> 3) & 7);         // pre-swizzled col slot
        const ushort* g = g0 + (size_t)row * DIM + c8 * 8;
        ushort* l = l0 + r * 4096 + (tid >> 6) * 512;  // wave-uniform base (+lane*16B HW)
        __builtin_amdgcn_global_load_lds(
            (const __attribute__((address_space(1))) uint32_t*)g,
            (__attribute__((address_space(3))) uint32_t*)l, 16, 0, 0);
    }
}

#define BARF()   do { __builtin_amdgcn_s_barrier(); \
                      asm volatile("" ::: "memory"); } while (0)
#define WAITL()  asm volatile("s_waitcnt lgkmcnt(0)" ::: "memory")
#define WAITV4() asm volatile("s_waitcnt vmcnt(4)" ::: "memory")
#define WAITV0() asm volatile("s_waitcnt vmcnt(0)" ::: "memory")
#define PRIO1()  __builtin_amdgcn_s_setprio(1)
#define PRIO0()  __builtin_amdgcn_s_setprio(0)

// swizzled ds_read of 16B fragments: row-major [*][64], col8 ^= (row&7) = (lane&7)
#define READ_A(AB, MH)                                                         \
    _Pragma("unroll") for (int m = 0; m < 4; ++m)                              \
    _Pragma("unroll") for (int k = 0; k < 2; ++k)                              \
        afr[m][k] = *(const short8*)&(AB)[                                     \
            (wr * 128 + ((MH) * 4 + m) * 16 + (lane & 15)) * 64 +              \
            (((k * 4 + (lane >> 4)) ^ (lane & 7)) * 8)];

#define READ_B(BB, NH)                                                         \
    _Pragma("unroll") for (int n = 0; n < 2; ++n)                              \
    _Pragma("unroll") for (int k = 0; k < 2; ++k)                              \
        bfr[(NH) * 2 + n][k] = *(const short8*)&(BB)[                          \
            (wc * 64 + ((NH) * 2 + n) * 16 + (lane & 15)) * 64 +               \
            (((k * 4 + (lane >> 4)) ^ (lane & 7)) * 8)];

#define MFMA_Q(MH, NH)                                                         \
    _Pragma("unroll") for (int m = 0; m < 4; ++m)                              \
    _Pragma("unroll") for (int n = 0; n < 2; ++n)                              \
    _Pragma("unroll") for (int k = 0; k < 2; ++k)                              \
        acc[(MH) * 4 + m][(NH) * 2 + n] =                                      \
            __builtin_amdgcn_mfma_f32_16x16x32_bf16(                           \
                afr[m][k], bfr[(NH) * 2 + n][k],                               \
                acc[(MH) * 4 + m][(NH) * 2 + n], 0, 0, 0);

// One K-tile = 4 phases. Stage plan (step S, buf s=S&1):
//   P1: A0(S+1)->s^1 (safe: s^1 unread this step)
//   P2: A1(S+1)->s^1 (safe)
//   P3: B0(S+2)->s   (safe: ALL B reads of s close at end-P2 barrier)
//   P4: B1(S+2)->s   (safe) + boundary s_waitcnt vmcnt(4)
// In-flight at boundary: {B0,B1}(S+2) = 4 loads. Never vmcnt(0) in-loop.
#define TILE_STEP(T, BUF)                                                      \
    {                                                                          \
        const ushort* Ab = &lds[(BUF) * BUF_EL];                               \
        const ushort* Bb = &lds[(BUF) * BUF_EL + ABUF_EL];                     \
        /* P1: Q(0,0) — 12 ds_reads */                                         \
        READ_A(Ab, 0);                                                         \
        READ_B(Bb, 0);                                                         \
        stage_ht(pb, lds, (T) + 1, 0, ibase, jbase, tid);                      \
        BARF(); WAITL();                                                       \
        PRIO1(); MFMA_Q(0, 0); PRIO0();                                        \
        BARF();                                                                \
        /* P2: Q(0,1) — 4 ds_reads */                                          \
        READ_B(Bb, 1);                                                         \
        stage_ht(pb, lds, (T) + 1, 1, ibase, jbase, tid);                      \
        BARF(); WAITL();                                                       \
        PRIO1(); MFMA_Q(0, 1); PRIO0();                                        \
        BARF();                                                                \
        /* P3: Q(1,0) — 8 ds_reads */                                          \
        READ_A(Ab, 1);                                                         \
        stage_ht(pb, lds, (T) + 2, 2, ibase, jbase, tid);                      \
        BARF(); WAITL();                                                       \
        PRIO1(); MFMA_Q(1, 0); PRIO0();                                        \
        BARF();                                                                \
        /* P4: Q(1,1) — 0 ds_reads, counted vmcnt at tile boundary */          \
        stage_ht(pb, lds, (T) + 2, 3, ibase, jbase, tid);                      \
        BARF(); WAITL();                                                       \
        PRIO1(); MFMA_Q(1, 1); PRIO0();                                        \
        WAITV4();                                                              \
        BARF();                                                                \
    }

// ---------------- kernel 2: 256² 8-phase triangular Gram + fused loss -------
__global__ __launch_bounds__(512) void tile2_kernel(
    const ushort* __restrict__ pb, const float* __restrict__ sq,
    const int* __restrict__ gt, double* __restrict__ accum) {

    __shared__ ushort lds[2 * BUF_EL];   // 128 KiB: 2 x (A[256][64] + B[256][64])
    __shared__ float wsum[8];

    int bid = (int)blockIdx.x;
    bid = (bid & 7) * (NTILES2 / 8) + (bid >> 3);   // bijective XCD swizzle (528=8*66)

    // triangular decode (ti <= tj): off(r) = r*NT2 - r(r-1)/2
    float fn = (float)NT2 + 0.5f;
    int r = (int)(fn - sqrtf(fn * fn - 2.0f * (float)bid));
    if (r < 0) r = 0;
    if (r >= NT2) r = NT2 - 1;
    while ((r + 1) * NT2 - ((r + 1) * r) / 2 <= bid) ++r;
    while (r * NT2 - (r * (r - 1)) / 2 > bid) --r;
    const int ti = r;
    const int tj = r + (bid - (r * NT2 - (r * (r - 1)) / 2));

    const int tid = threadIdx.x;
    const int lane = tid & 63;
    const int wv = tid >> 6;
    const int wr = wv >> 2;   // 0..1 : wave row (128 rows each)
    const int wc = wv & 3;    // 0..3 : wave col (64 cols each)
    const int ibase = ti * BT2;
    const int jbase = tj * BT2;

    floatx4 acc[8][4] = {};
    short8 afr[4][2];
    short8 bfr[4][2];

    // prologue: tile0 {B0,B1,A0,A1}, tile1 {B0,B1}; vmcnt(4) -> tile0 resident,
    // in-flight = {B0,B1}(1) — matches the steady-state invariant.
    stage_ht(pb, lds, 0, 2, ibase, jbase, tid);
    stage_ht(pb, lds, 0, 3, ibase, jbase, tid);
    stage_ht(pb, lds, 0, 0, ibase, jbase, tid);
    stage_ht(pb, lds, 0, 1, ibase, jbase, tid);
    stage_ht(pb, lds, 1, 2, ibase, jbase, tid);
    stage_ht(pb, lds, 1, 3, ibase, jbase, tid);
    WAITV4();
    BARF();

    for (int u2 = 0; u2 < NKT / 2; ++u2) {
        TILE_STEP(u2 * 2, 0);
        TILE_STEP(u2 * 2 + 1, 1);
    }
    WAITV0();   // drain tail stages before exit
    BARF();

    // fused epilogue: d2 -> contrastive term -> weighted partial sum
    const float invd = 1.0f / (float)DIM;
    float lsum = 0.f;
    {
        int j0 = jbase + wc * 64 + (lane & 15);
        float sqj[4]; int gj[4];
#pragma unroll
        for (int n = 0; n < 4; ++n) { int j = j0 + n * 16; sqj[n] = sq[j]; gj[n] = gt[j]; }
        const float wb = (ti != tj) ? 2.0f : 1.0f;
#pragma unroll
        for (int mi = 0; mi < 8; ++mi) {
#pragma unroll
            for (int rr = 0; rr < 4; ++rr) {
                int i = ibase + wr * 128 + mi * 16 + (lane >> 4) * 4 + rr;
                float sqi = sq[i];
                int gi = gt[i];
#pragma unroll
                for (int n = 0; n < 4; ++n) {
                    int j = j0 + n * 16;
                    float d2 = fmaxf(sqi + sqj[n] - 2.0f * acc[mi][n][rr], 0.0f) * invd;
                    float term = (gi == gj[n]) ? d2 : fmaxf(MARGIN - d2, 0.0f);
                    float w = wb;
                    if (ti == tj && i == j) w = 2.0f;   // triu diagonal counted once*2
                    lsum += w * term;
                }
            }
        }
    }
#pragma unroll
    for (int o = 32; o > 0; o >>= 1) lsum += __shfl_down(lsum, o, 64);
    if (lane == 0) wsum[wv] = lsum;
    __syncthreads();
    if (tid == 0) {
        float s = 0.f;
#pragma unroll
        for (int w = 0; w < 8; ++w) s += wsum[w];
        atomicAdd(accum, (double)s);
    }
}

// ---------------- kernel 3: finalize ----------------------------------------
__global__ void finalize_kernel(const double* __restrict__ accum,
                                float* __restrict__ out) {
    if (threadIdx.x == 0)
        out[0] = (float)(accum[0] * (1.0 / ((double)NROWS * (double)(NROWS - 1))));
}

extern "C" void kernel_launch(void* const* d_in, const int* in_sizes, int n_in,
                              void* d_out, int out_size, void* d_ws, size_t ws_size,
                              hipStream_t stream) {
    (void)in_sizes; (void)n_in; (void)out_size; (void)ws_size;
    const float* p = (const float*)d_in[0];
    const int* gt = (const int*)d_in[1];
    float* out = (float*)d_out;

    ushort* pb = (ushort*)d_ws;                                   // 32 MB bf16
    float* sq = (float*)((char*)d_ws + (size_t)NROWS * DIM * 2);  // 32 KB
    double* accum = (double*)((char*)d_ws + (size_t)NROWS * DIM * 2
                              + (size_t)NROWS * sizeof(float));   // 8 B

    (void)hipMemsetAsync(accum, 0, sizeof(double), stream);
    prep_kernel<<<NROWS, 256, 0, stream>>>(p, pb, sq);
    tile2_kernel<<<NTILES2, 512, 0, stream>>>(pb, sq, gt, accum);
    finalize_kernel<<<1, 64, 0, stream>>>(accum, out);
}